// Round 1
// baseline (162.449 us; speedup 1.0000x reference)
//
#include <hip/hip_runtime.h>

// Problem constants (reference: N=4, L=4096, S=4096, H=8, D=64, fp32 in/out)
#define NB   4
#define LQ   4096
#define SK   4096
#define NHD  8
#define DD   64
#define ROWSTRIDE (NHD * DD)      // 512 floats between consecutive s (or l) rows
#define CH   16                   // S-chunks per (n,h)
#define SROWS (SK / CH)           // 256 rows per chunk
#define TS   16                   // LDS staging rows
#define KVSZ (DD * DD)            // 4096
#define PART_STRIDE (KVSZ + DD)   // 4160: KV + Ksum
#define NHTOT (NB * NHD)          // 32
#define LT   64                   // L rows per k3 block
#define EPSF 1e-6f

__device__ __forceinline__ float fmap(float x) {
    // elu(x) + 1 == x+1 (x>0) else exp(x)
    return x > 0.f ? x + 1.f : __expf(x);
}

// ---------------------------------------------------------------------------
// k1: partial KV[d][e] = sum_s K[s][d]*V[s][e]  and  Ksum[d] = sum_s K[s][d]
// grid: NHTOT*CH blocks, 256 threads. Each block: 256 s-rows of one (n,h).
// ---------------------------------------------------------------------------
__global__ __launch_bounds__(256) void k1_kv(const float* __restrict__ Kin,
                                             const float* __restrict__ Vin,
                                             float* __restrict__ part) {
    const int blk   = blockIdx.x;
    const int nh    = blk / CH;
    const int chunk = blk % CH;
    const int n = nh / NHD, h = nh % NHD;
    const int t = threadIdx.x;
    const int r  = t >> 4;          // 0..15 staging row
    const int c  = (t & 15) << 2;   // 0,4,..,60 staging col
    const int d0 = c;               // this thread's KV d-range
    const int e0 = r << 2;          // this thread's KV e-range

    __shared__ __align__(16) float Ks[TS][DD];
    __shared__ __align__(16) float Vs[TS][DD];
    __shared__ __align__(16) float ksred[TS][DD];

    float acc[4][4] = {};
    float ksl[4] = {0.f, 0.f, 0.f, 0.f};

    const size_t base = ((size_t)n * SK + (size_t)chunk * SROWS) * ROWSTRIDE
                        + (size_t)h * DD;

    for (int s0 = 0; s0 < SROWS; s0 += TS) {
        const size_t g = base + (size_t)(s0 + r) * ROWSTRIDE + c;
        float4 kg = *(const float4*)(Kin + g);
        float4 vg = *(const float4*)(Vin + g);
        float4 kf;
        kf.x = fmap(kg.x); kf.y = fmap(kg.y); kf.z = fmap(kg.z); kf.w = fmap(kg.w);
        // Ksum partial: this thread stages exactly rows s0+r, cols c..c+3
        ksl[0] += kf.x; ksl[1] += kf.y; ksl[2] += kf.z; ksl[3] += kf.w;
        __syncthreads();                 // prior iter's reads done
        *(float4*)&Ks[r][c] = kf;
        *(float4*)&Vs[r][c] = vg;
        __syncthreads();                 // stores visible
#pragma unroll
        for (int s = 0; s < TS; ++s) {
            float4 k4 = *(float4*)&Ks[s][d0];
            float4 v4 = *(float4*)&Vs[s][e0];
            float kk[4] = {k4.x, k4.y, k4.z, k4.w};
            float vv[4] = {v4.x, v4.y, v4.z, v4.w};
#pragma unroll
            for (int i = 0; i < 4; ++i)
#pragma unroll
                for (int j = 0; j < 4; ++j)
                    acc[i][j] += kk[i] * vv[j];
        }
    }

    // reduce Ksum partials across the 16 r-groups
    __syncthreads();
    *(float4*)&ksred[r][c] = make_float4(ksl[0], ksl[1], ksl[2], ksl[3]);
    __syncthreads();

    float* pb = part + ((size_t)nh * CH + chunk) * PART_STRIDE;
    if (t < DD) {
        float s = 0.f;
#pragma unroll
        for (int rr = 0; rr < TS; ++rr) s += ksred[rr][t];
        pb[KVSZ + t] = s;
    }
#pragma unroll
    for (int i = 0; i < 4; ++i) {
        float4 o = make_float4(acc[i][0], acc[i][1], acc[i][2], acc[i][3]);
        *(float4*)(pb + (d0 + i) * DD + e0) = o;
    }
}

// ---------------------------------------------------------------------------
// k2: sum CH partials -> final [nh][4160]
// ---------------------------------------------------------------------------
__global__ __launch_bounds__(256) void k2_reduce(const float* __restrict__ part,
                                                 float* __restrict__ fin) {
    const int idx = blockIdx.x * 256 + threadIdx.x;
    if (idx >= NHTOT * PART_STRIDE) return;
    const int nh = idx / PART_STRIDE;
    const int j  = idx - nh * PART_STRIDE;
    const float* p = part + (size_t)nh * CH * PART_STRIDE + j;
    float s = 0.f;
#pragma unroll
    for (int cix = 0; cix < CH; ++cix) s += p[(size_t)cix * PART_STRIDE];
    fin[idx] = s;
}

// ---------------------------------------------------------------------------
// k3: out[l][e] = (sum_d Q[l][d]*KV[d][e]) / (sum_d Q[l][d]*Ksum[d] + eps)
// grid: NHTOT * (LQ/LT) blocks, 256 threads; 4x4 register tile per thread.
// ---------------------------------------------------------------------------
#define QPAD 68   // stride 68: 16B-aligned float4 rows, banks evenly spread
__global__ __launch_bounds__(256) void k3_out(const float* __restrict__ Qin,
                                              const float* __restrict__ fin,
                                              float* __restrict__ out) {
    const int blk = blockIdx.x;
    const int nh  = blk >> 6;        // /64
    const int lc  = blk & 63;
    const int n = nh >> 3, h = nh & 7;
    const int t = threadIdx.x;

    __shared__ __align__(16) float KVs[DD][DD];   // [d][e]
    __shared__ __align__(16) float Ksm[DD];
    __shared__ __align__(16) float Qs[LT][QPAD];  // [l][d], padded

    // load final KV + Ksum for this (n,h)
    const float* fb = fin + (size_t)nh * PART_STRIDE;
    float* kvflat = &KVs[0][0];
    for (int i = t * 4; i < KVSZ; i += 1024)
        *(float4*)(kvflat + i) = *(const float4*)(fb + i);
    if (t < DD) Ksm[t] = fb[KVSZ + t];

    // load + feature-map Q chunk
    const int r = t >> 4;
    const int c = (t & 15) << 2;
    const size_t qbase = ((size_t)n * LQ + (size_t)lc * LT) * ROWSTRIDE
                         + (size_t)h * DD;
    for (int rr = r; rr < LT; rr += 16) {
        float4 q = *(const float4*)(Qin + qbase + (size_t)rr * ROWSTRIDE + c);
        float4 qf;
        qf.x = fmap(q.x); qf.y = fmap(q.y); qf.z = fmap(q.z); qf.w = fmap(q.w);
        *(float4*)&Qs[rr][c] = qf;
    }
    __syncthreads();

    const int e0 = (t & 15) << 2;
    const int l0 = (t >> 4) << 2;
    float acc[4][4] = {};
    float z[4] = {0.f, 0.f, 0.f, 0.f};

#pragma unroll 4
    for (int d0 = 0; d0 < DD; d0 += 4) {
        float4 km4 = *(float4*)&Ksm[d0];
        float km[4] = {km4.x, km4.y, km4.z, km4.w};
        float q[4][4];
        float kv[4][4];
#pragma unroll
        for (int i = 0; i < 4; ++i) {
            float4 q4 = *(float4*)&Qs[l0 + i][d0];
            q[i][0] = q4.x; q[i][1] = q4.y; q[i][2] = q4.z; q[i][3] = q4.w;
        }
#pragma unroll
        for (int s = 0; s < 4; ++s) {
            float4 kv4 = *(float4*)&KVs[d0 + s][e0];
            kv[s][0] = kv4.x; kv[s][1] = kv4.y; kv[s][2] = kv4.z; kv[s][3] = kv4.w;
        }
#pragma unroll
        for (int i = 0; i < 4; ++i)
#pragma unroll
            for (int s = 0; s < 4; ++s) {
                z[i] += q[i][s] * km[s];
#pragma unroll
                for (int j = 0; j < 4; ++j)
                    acc[i][j] += q[i][s] * kv[s][j];
            }
    }

#pragma unroll
    for (int i = 0; i < 4; ++i) {
        float zi = 1.f / (z[i] + EPSF);
        float4 o = make_float4(acc[i][0] * zi, acc[i][1] * zi,
                               acc[i][2] * zi, acc[i][3] * zi);
        *(float4*)(out + ((size_t)n * LQ + (size_t)lc * LT + l0 + i) * ROWSTRIDE
                   + (size_t)h * DD + e0) = o;
    }
}

// ---------------------------------------------------------------------------
extern "C" void kernel_launch(void* const* d_in, const int* in_sizes, int n_in,
                              void* d_out, int out_size, void* d_ws, size_t ws_size,
                              hipStream_t stream) {
    const float* Q = (const float*)d_in[0];
    const float* K = (const float*)d_in[1];
    const float* V = (const float*)d_in[2];
    float* out = (float*)d_out;

    float* ws   = (float*)d_ws;
    float* part = ws;                                        // 32*16*4160 floats
    float* fin  = ws + (size_t)NHTOT * CH * PART_STRIDE;     // 32*4160 floats
    // total ws use: ~9.1 MB

    k1_kv<<<NHTOT * CH, 256, 0, stream>>>(K, V, part);
    k2_reduce<<<(NHTOT * PART_STRIDE + 255) / 256, 256, 0, stream>>>(part, fin);
    k3_out<<<NHTOT * (LQ / LT), 256, 0, stream>>>(Q, fin, out);
}